// Round 1
// baseline (1102.291 us; speedup 1.0000x reference)
//
#include <hip/hip_runtime.h>

#define MAXT 16
#define DDIM 1024
#define NTHREADS 256   // 256 threads * float4 = 1024 = DDIM, one float4/thread/depth

__global__ __launch_bounds__(NTHREADS)
void attn_depth_kernel(const float* __restrict__ entries,
                       const float* __restrict__ proj,
                       const float* __restrict__ norm_scale,
                       const int* __restrict__ n_active_p,
                       const int* __restrict__ block_idx_p,
                       float* __restrict__ out,
                       int BS)
{
    const int site = blockIdx.x;          // b*S + s
    const int tid  = threadIdx.x;
    const int d0   = tid * 4;

    int n_act = *n_active_p;
    n_act = n_act < 0 ? 0 : (n_act > MAXT ? MAXT : n_act);
    int row = *block_idx_p;
    row = row > (MAXT - 1) ? (MAXT - 1) : (row < 0 ? 0 : row);

    // q[d] = proj[row][d] * norm_scale[d]  (tiny, L2/L1 cached)
    float4 q  = *reinterpret_cast<const float4*>(proj + (size_t)row * DDIM + d0);
    float4 ns = *reinterpret_cast<const float4*>(norm_scale + d0);
    q.x *= ns.x; q.y *= ns.y; q.z *= ns.z; q.w *= ns.w;

    const size_t siteOff = (size_t)site * DDIM + d0;
    const size_t tStride = (size_t)BS * DDIM;
    const float* base = entries + siteOff;

    // Register-resident entry slices: 16 * float4 = 64 VGPRs of payload.
    float4 e[MAXT];
    float  ss[MAXT];   // per-t sum of squares (partial)
    float  dt[MAXT];   // per-t dot with q     (partial)

#pragma unroll
    for (int t = 0; t < MAXT; ++t) {
        e[t]  = make_float4(0.f, 0.f, 0.f, 0.f);
        ss[t] = 0.f;
        dt[t] = 0.f;
        if (t < n_act) {   // wave-uniform branch; skips HBM reads of masked depths
            float4 v = *reinterpret_cast<const float4*>(base + (size_t)t * tStride);
            e[t]  = v;
            ss[t] = v.x*v.x + v.y*v.y + v.z*v.z + v.w*v.w;
            dt[t] = q.x*v.x + q.y*v.y + q.z*v.z + q.w*v.w;
        }
    }

    // Per-wave 64-lane butterfly reduction of (ss, dt) for each active t.
#pragma unroll
    for (int t = 0; t < MAXT; ++t) {
        if (t < n_act) {
            float s = ss[t], d = dt[t];
#pragma unroll
            for (int off = 32; off >= 1; off >>= 1) {
                s += __shfl_xor(s, off, 64);
                d += __shfl_xor(d, off, 64);
            }
            ss[t] = s; dt[t] = d;
        }
    }

    // Combine the 4 wave partials through LDS (512 B).
    __shared__ float red_ss[NTHREADS / 64][MAXT];
    __shared__ float red_dt[NTHREADS / 64][MAXT];
    const int wave = tid >> 6;
    const int lane = tid & 63;
    if (lane == 0) {
#pragma unroll
        for (int t = 0; t < MAXT; ++t) {
            red_ss[wave][t] = ss[t];
            red_dt[wave][t] = dt[t];
        }
    }
    __syncthreads();

    // Every thread redundantly computes the 16-wide softmax (cheap VALU).
    float w[MAXT];
    float m = -3.0e38f;
#pragma unroll
    for (int t = 0; t < MAXT; ++t) {
        w[t] = 0.f;
        if (t < n_act) {
            float s = red_ss[0][t] + red_ss[1][t] + red_ss[2][t] + red_ss[3][t];
            float d = red_dt[0][t] + red_dt[1][t] + red_dt[2][t] + red_dt[3][t];
            // logit = dot(q, e/rms) = dot / sqrt(mean(e^2) + eps)
            float logit = d * rsqrtf(s * (1.0f / DDIM) + 1e-5f);
            w[t] = logit;
            m = fmaxf(m, logit);
        }
    }
    float sum = 0.f;
#pragma unroll
    for (int t = 0; t < MAXT; ++t) {
        if (t < n_act) { w[t] = __expf(w[t] - m); sum += w[t]; }
    }
    const float inv = 1.0f / sum;

    float4 acc = make_float4(0.f, 0.f, 0.f, 0.f);
#pragma unroll
    for (int t = 0; t < MAXT; ++t) {
        const float wt = w[t] * inv;   // 0 for masked t
        acc.x += wt * e[t].x;
        acc.y += wt * e[t].y;
        acc.z += wt * e[t].z;
        acc.w += wt * e[t].w;
    }
    *reinterpret_cast<float4*>(out + siteOff) = acc;
}

extern "C" void kernel_launch(void* const* d_in, const int* in_sizes, int n_in,
                              void* d_out, int out_size, void* d_ws, size_t ws_size,
                              hipStream_t stream)
{
    const float* entries = (const float*)d_in[0];
    const float* proj    = (const float*)d_in[1];
    const float* nscale  = (const float*)d_in[2];
    const int*   n_act   = (const int*)d_in[3];
    const int*   bidx    = (const int*)d_in[4];
    float*       out     = (float*)d_out;

    const int BS = out_size / DDIM;   // B*S = 16384
    attn_depth_kernel<<<BS, NTHREADS, 0, stream>>>(entries, proj, nscale,
                                                   n_act, bidx, out, BS);
}

// Round 2
// 491.639 us; speedup vs baseline: 2.2421x; 2.2421x over previous
//
#include <hip/hip_runtime.h>

#define MAXT 16
#define DDIM 1024
#define NTHREADS 256   // 256 threads * float4 = 1024 = DDIM, one float4/thread/depth

__global__ __launch_bounds__(NTHREADS)
void attn_depth_kernel(const float* __restrict__ entries,
                       const float* __restrict__ proj,
                       const float* __restrict__ norm_scale,
                       const int* __restrict__ n_active_p,
                       const int* __restrict__ block_idx_p,
                       float* __restrict__ out,
                       int BS)
{
    const int site = blockIdx.x;          // b*S + s
    const int tid  = threadIdx.x;
    const int d0   = tid * 4;

    int n_act = *n_active_p;
    n_act = n_act < 1 ? 1 : (n_act > MAXT ? MAXT : n_act);
    int row = *block_idx_p;
    row = row > (MAXT - 1) ? (MAXT - 1) : (row < 0 ? 0 : row);

    // q[d] = proj[row][d] * norm_scale[d]  (tiny, cached)
    float4 q  = *reinterpret_cast<const float4*>(proj + (size_t)row * DDIM + d0);
    float4 ns = *reinterpret_cast<const float4*>(norm_scale + d0);
    q.x *= ns.x; q.y *= ns.y; q.z *= ns.z; q.w *= ns.w;

    const size_t siteOff = (size_t)site * DDIM + d0;
    const size_t tStride = (size_t)BS * DDIM;
    const float* base = entries + siteOff;

    // Issue ALL loads before any use. Clamped depth index keeps the stream
    // branch-free (masked t re-reads slice n_act-1 -> L1 hit, no extra HBM),
    // so all 16 float4 loads are in flight simultaneously (full MLP).
    float4 e[MAXT];
#pragma unroll
    for (int t = 0; t < MAXT; ++t) {
        const int tl = t < n_act ? t : (n_act - 1);   // wave-uniform SALU select
        e[t] = *reinterpret_cast<const float4*>(base + (size_t)tl * tStride);
    }

    // Partials computed AFTER all loads are issued -> progressive vmcnt waits.
    float ss[MAXT];   // per-t sum of squares (partial)
    float dt[MAXT];   // per-t dot with q     (partial)
#pragma unroll
    for (int t = 0; t < MAXT; ++t) {
        const float4 v = e[t];
        ss[t] = v.x*v.x + v.y*v.y + v.z*v.z + v.w*v.w;
        dt[t] = q.x*v.x + q.y*v.y + q.z*v.z + q.w*v.w;
    }

    // Per-wave 64-lane butterfly reduction of (ss, dt) for each active t.
#pragma unroll
    for (int t = 0; t < MAXT; ++t) {
        if (t < n_act) {
            float s = ss[t], d = dt[t];
#pragma unroll
            for (int off = 32; off >= 1; off >>= 1) {
                s += __shfl_xor(s, off, 64);
                d += __shfl_xor(d, off, 64);
            }
            ss[t] = s; dt[t] = d;
        }
    }

    // Combine the 4 wave partials through LDS (512 B).
    __shared__ float red_ss[NTHREADS / 64][MAXT];
    __shared__ float red_dt[NTHREADS / 64][MAXT];
    const int wave = tid >> 6;
    const int lane = tid & 63;
    if (lane == 0) {
#pragma unroll
        for (int t = 0; t < MAXT; ++t) {
            red_ss[wave][t] = ss[t];
            red_dt[wave][t] = dt[t];
        }
    }
    __syncthreads();

    // Every thread redundantly computes the 16-wide softmax (cheap VALU).
    float w[MAXT];
    float m = -3.0e38f;
#pragma unroll
    for (int t = 0; t < MAXT; ++t) {
        w[t] = 0.f;
        if (t < n_act) {
            float s = red_ss[0][t] + red_ss[1][t] + red_ss[2][t] + red_ss[3][t];
            float d = red_dt[0][t] + red_dt[1][t] + red_dt[2][t] + red_dt[3][t];
            // logit = dot(q, e/rms) = dot / sqrt(mean(e^2) + eps)
            float logit = d * rsqrtf(s * (1.0f / DDIM) + 1e-5f);
            w[t] = logit;
            m = fmaxf(m, logit);
        }
    }
    float sum = 0.f;
#pragma unroll
    for (int t = 0; t < MAXT; ++t) {
        if (t < n_act) { w[t] = __expf(w[t] - m); sum += w[t]; }
    }
    const float inv = 1.0f / sum;

    // Weighted sum; masked t contribute exactly 0 (w[t]==0, 0*garbage==0).
    float4 acc = make_float4(0.f, 0.f, 0.f, 0.f);
#pragma unroll
    for (int t = 0; t < MAXT; ++t) {
        const float wt = w[t] * inv;
        acc.x += wt * e[t].x;
        acc.y += wt * e[t].y;
        acc.z += wt * e[t].z;
        acc.w += wt * e[t].w;
    }
    *reinterpret_cast<float4*>(out + siteOff) = acc;
}

extern "C" void kernel_launch(void* const* d_in, const int* in_sizes, int n_in,
                              void* d_out, int out_size, void* d_ws, size_t ws_size,
                              hipStream_t stream)
{
    const float* entries = (const float*)d_in[0];
    const float* proj    = (const float*)d_in[1];
    const float* nscale  = (const float*)d_in[2];
    const int*   n_act   = (const int*)d_in[3];
    const int*   bidx    = (const int*)d_in[4];
    float*       out     = (float*)d_out;

    const int BS = out_size / DDIM;   // B*S = 16384
    attn_depth_kernel<<<BS, NTHREADS, 0, stream>>>(entries, proj, nscale,
                                                   n_act, bidx, out, BS);
}

// Round 3
// 165.515 us; speedup vs baseline: 6.6598x; 2.9704x over previous
//
#include <hip/hip_runtime.h>

#define MAXT 16
#define DDIM 1024
#define NTHREADS 256
#define TPW 4          // depths per wave (4 waves x 4 = 16 = MAXT)

__global__ __launch_bounds__(NTHREADS, 3)
void attn_depth_kernel(const float* __restrict__ entries,
                       const float* __restrict__ proj,
                       const float* __restrict__ norm_scale,
                       const int* __restrict__ n_active_p,
                       const int* __restrict__ block_idx_p,
                       float* __restrict__ out,
                       int BS)
{
    const int site = blockIdx.x;          // b*S + s
    const int tid  = threadIdx.x;
    const int wave = tid >> 6;
    const int lane = tid & 63;

    int n_act = *n_active_p;
    n_act = n_act < 1 ? 1 : (n_act > MAXT ? MAXT : n_act);
    int row = *block_idx_p;
    row = row > (MAXT - 1) ? (MAXT - 1) : (row < 0 ? 0 : row);

    // This thread's d-elements: d(c,j) = c*256 + lane*4 + j, c = 0..3
    const int dbase = lane * 4;

    const size_t tStride = (size_t)BS * DDIM;
    const float* ebase = entries + (size_t)site * DDIM + dbase;

    // Wave w owns depths t = 4w..4w+3; lanes jointly cover the full 1024-d row.
    // Masked depths: skip the loads (zero regs) -> exactly 12/16 slices hit HBM.
    float4 e[TPW][4];
#pragma unroll
    for (int tt = 0; tt < TPW; ++tt) {
        const int t = wave * TPW + tt;          // wave-uniform
        if (t < n_act) {
#pragma unroll
            for (int c = 0; c < 4; ++c)
                e[tt][c] = *reinterpret_cast<const float4*>(ebase + (size_t)t * tStride + c * 256);
        } else {
#pragma unroll
            for (int c = 0; c < 4; ++c)
                e[tt][c] = make_float4(0.f, 0.f, 0.f, 0.f);
        }
    }

    // q = proj[row] * norm_scale at this thread's d-elements (cached, tiny)
    float4 q[4];
#pragma unroll
    for (int c = 0; c < 4; ++c) {
        float4 p  = *reinterpret_cast<const float4*>(proj + (size_t)row * DDIM + c * 256 + dbase);
        float4 ns = *reinterpret_cast<const float4*>(norm_scale + c * 256 + dbase);
        q[c] = make_float4(p.x * ns.x, p.y * ns.y, p.z * ns.z, p.w * ns.w);
    }

    // Per-depth partials over this thread's 16 elements
    float ss[TPW], dt[TPW];
#pragma unroll
    for (int tt = 0; tt < TPW; ++tt) {
        float s = 0.f, d = 0.f;
#pragma unroll
        for (int c = 0; c < 4; ++c) {
            const float4 v = e[tt][c];
            s = fmaf(v.x, v.x, s); s = fmaf(v.y, v.y, s);
            s = fmaf(v.z, v.z, s); s = fmaf(v.w, v.w, s);
            d = fmaf(q[c].x, v.x, d); d = fmaf(q[c].y, v.y, d);
            d = fmaf(q[c].z, v.z, d); d = fmaf(q[c].w, v.w, d);
        }
        ss[tt] = s; dt[tt] = d;
    }

    // 64-lane butterfly; 8 independent chains (4 depths x 2 values) for ILP.
    // Only 48 shuffles/thread vs 192 in the all-depths-per-wave layout.
#pragma unroll
    for (int off = 32; off >= 1; off >>= 1) {
#pragma unroll
        for (int tt = 0; tt < TPW; ++tt) {
            ss[tt] += __shfl_xor(ss[tt], off, 64);
            dt[tt] += __shfl_xor(dt[tt], off, 64);
        }
    }

    __shared__ float red[2 * MAXT];        // [0..15]=ss, [16..31]=dt
    __shared__ float part[TPW][DDIM];      // per-wave partial outputs (16 KB)

    if (lane == 0) {
        *reinterpret_cast<float4*>(&red[wave * TPW])        = make_float4(ss[0], ss[1], ss[2], ss[3]);
        *reinterpret_cast<float4*>(&red[MAXT + wave * TPW]) = make_float4(dt[0], dt[1], dt[2], dt[3]);
    }
    __syncthreads();

    // Redundant per-thread softmax stats (m, sum) over all 16 depths.
    float lg[MAXT];
    float4 rs[4], rd[4];
#pragma unroll
    for (int c = 0; c < 4; ++c) {
        rs[c] = *reinterpret_cast<const float4*>(&red[c * 4]);
        rd[c] = *reinterpret_cast<const float4*>(&red[MAXT + c * 4]);
    }
#pragma unroll
    for (int c = 0; c < 4; ++c) {
        lg[c * 4 + 0] = rd[c].x * rsqrtf(rs[c].x * (1.f / DDIM) + 1e-5f);
        lg[c * 4 + 1] = rd[c].y * rsqrtf(rs[c].y * (1.f / DDIM) + 1e-5f);
        lg[c * 4 + 2] = rd[c].z * rsqrtf(rs[c].z * (1.f / DDIM) + 1e-5f);
        lg[c * 4 + 3] = rd[c].w * rsqrtf(rs[c].w * (1.f / DDIM) + 1e-5f);
    }
    float m = -3.0e38f;
#pragma unroll
    for (int t = 0; t < MAXT; ++t)
        if (t < n_act) m = fmaxf(m, lg[t]);
    float sum = 0.f;
#pragma unroll
    for (int t = 0; t < MAXT; ++t)
        if (t < n_act) sum += __expf(lg[t] - m);
    const float inv = 1.f / sum;

    // This wave's 4 weights: recomputed from LDS at runtime ADDRESS (no dynamic
    // register indexing -> no scratch).
    float wt[TPW];
#pragma unroll
    for (int tt = 0; tt < TPW; ++tt) {
        const int t = wave * TPW + tt;
        const float s_ = red[t];
        const float d_ = red[MAXT + t];
        const float l_ = d_ * rsqrtf(s_ * (1.f / DDIM) + 1e-5f);
        wt[tt] = (t < n_act) ? __expf(l_ - m) * inv : 0.f;
    }

    // Weighted partial over this wave's depths (masked t: wt==0 and e==0).
    float4 acc[4];
#pragma unroll
    for (int c = 0; c < 4; ++c) acc[c] = make_float4(0.f, 0.f, 0.f, 0.f);
#pragma unroll
    for (int tt = 0; tt < TPW; ++tt) {
#pragma unroll
        for (int c = 0; c < 4; ++c) {
            acc[c].x = fmaf(wt[tt], e[tt][c].x, acc[c].x);
            acc[c].y = fmaf(wt[tt], e[tt][c].y, acc[c].y);
            acc[c].z = fmaf(wt[tt], e[tt][c].z, acc[c].z);
            acc[c].w = fmaf(wt[tt], e[tt][c].w, acc[c].w);
        }
    }
#pragma unroll
    for (int c = 0; c < 4; ++c)
        *reinterpret_cast<float4*>(&part[wave][c * 256 + dbase]) = acc[c];
    __syncthreads();

    // Cross-wave combine: thread owns out[tid*4 .. tid*4+3].
    const int od = tid * 4;
    float4 r0 = *reinterpret_cast<const float4*>(&part[0][od]);
    float4 r1 = *reinterpret_cast<const float4*>(&part[1][od]);
    float4 r2 = *reinterpret_cast<const float4*>(&part[2][od]);
    float4 r3 = *reinterpret_cast<const float4*>(&part[3][od]);
    float4 r;
    r.x = (r0.x + r1.x) + (r2.x + r3.x);
    r.y = (r0.y + r1.y) + (r2.y + r3.y);
    r.z = (r0.z + r1.z) + (r2.z + r3.z);
    r.w = (r0.w + r1.w) + (r2.w + r3.w);
    *reinterpret_cast<float4*>(out + (size_t)site * DDIM + od) = r;
}

extern "C" void kernel_launch(void* const* d_in, const int* in_sizes, int n_in,
                              void* d_out, int out_size, void* d_ws, size_t ws_size,
                              hipStream_t stream)
{
    const float* entries = (const float*)d_in[0];
    const float* proj    = (const float*)d_in[1];
    const float* nscale  = (const float*)d_in[2];
    const int*   n_act   = (const int*)d_in[3];
    const int*   bidx    = (const int*)d_in[4];
    float*       out     = (float*)d_out;

    const int BS = out_size / DDIM;   // B*S = 16384
    attn_depth_kernel<<<BS, NTHREADS, 0, stream>>>(entries, proj, nscale,
                                                   n_act, bidx, out, BS);
}